// Round 9
// baseline (678.123 us; speedup 1.0000x reference)
//
#include <hip/hip_runtime.h>
#include <stdint.h>

typedef unsigned int u32;
typedef unsigned short u16;
typedef unsigned long long u64;
typedef __attribute__((ext_vector_type(8))) __bf16 bf16x8;
typedef __attribute__((ext_vector_type(4))) float f32x4;

#define N_ROWS 32768
#define D_DIM 512
#define K_CB 1024

__host__ __device__ inline u32 rotl32(u32 x, int r) {
#ifdef __HIP_DEVICE_COMPILE__
  return __builtin_amdgcn_alignbit(x, x, 32 - r); // rotr(32-r) == rotl(r)
#else
  return (x << r) | (x >> (32 - r));
#endif
}

// ---------------- threefry2x32 (matches jax._src.prng, partitionable) ----------------
__host__ __device__ inline void tf2x32(u32 k0, u32 k1, u32 x0, u32 x1, u32 &o0, u32 &o1) {
  const u32 ks2 = k0 ^ k1 ^ 0x1BD11BDAu;
#define TFR(r) x0 += x1; x1 = rotl32(x1, r); x1 ^= x0;
  x0 += k0; x1 += k1;
  TFR(13) TFR(15) TFR(26) TFR(6)
  x0 += k1; x1 += ks2 + 1u;
  TFR(17) TFR(29) TFR(16) TFR(24)
  x0 += ks2; x1 += k0 + 2u;
  TFR(13) TFR(15) TFR(26) TFR(6)
  x0 += k0; x1 += k1 + 3u;
  TFR(17) TFR(29) TFR(16) TFR(24)
  x0 += k1; x1 += ks2 + 4u;
  TFR(13) TFR(15) TFR(26) TFR(6)
  x0 += ks2; x1 += k0 + 5u;
#undef TFR
  o0 = x0; o1 = x1;
}

// gumbel = -log(-log(max(tiny, f+tiny))) via native v_log_f32
__device__ inline float gumbel_fast(u32 bits) {
  const float f = __uint_as_float((bits >> 9) | 0x3f800000u) - 1.0f; // [0,1)
  const float tiny = 1.17549435e-38f;
  const float u = fmaxf(tiny, f + tiny);
  const float NLN2 = -0.69314718055994530942f;
  const float a = __log2f(u);
  const float v = a * NLN2;   // -log(u) in (0, 87.4]
  return __log2f(v) * NLN2;   // in [-4.48, 16.7]
}

__device__ inline u16 f32_bf16(float x) { // RNE
  u32 u = __float_as_uint(x);
  u += 0x7fffu + ((u >> 16) & 1u);
  return (u16)(u >> 16);
}
__device__ inline float bf16_f32(u16 h) { return __uint_as_float(((u32)h) << 16); }

// ---------------- prep: normalize codebook, split to bf16 hi/lo ----------------
__global__ void __launch_bounds__(256) prep_codebook(const float* __restrict__ cb,
                                                     u16* __restrict__ cn_hi,
                                                     u16* __restrict__ cn_lo) {
  const int lane = threadIdx.x & 63, wid = threadIdx.x >> 6;
  const int row = blockIdx.x * 4 + wid;
  const float4* src = (const float4*)(cb + (size_t)row * D_DIM);
  float4 v[2]; float ss = 0.f;
#pragma unroll
  for (int i = 0; i < 2; ++i) {
    v[i] = src[lane + 64 * i];
    ss = fmaf(v[i].x, v[i].x, ss); ss = fmaf(v[i].y, v[i].y, ss);
    ss = fmaf(v[i].z, v[i].z, ss); ss = fmaf(v[i].w, v[i].w, ss);
  }
#pragma unroll
  for (int off = 32; off; off >>= 1) ss += __shfl_xor(ss, off);
  const float inv = 1.0f / fmaxf(sqrtf(ss), 1e-8f);
  ushort4* dhi = (ushort4*)(cn_hi + (size_t)row * D_DIM);
  ushort4* dlo = (ushort4*)(cn_lo + (size_t)row * D_DIM);
#pragma unroll
  for (int i = 0; i < 2; ++i) {
    const float c[4] = {v[i].x * inv, v[i].y * inv, v[i].z * inv, v[i].w * inv};
    ushort4 h4, l4;
    u16* hp = (u16*)&h4; u16* lp = (u16*)&l4;
#pragma unroll
    for (int j = 0; j < 4; ++j) {
      const u16 h = f32_bf16(c[j]);
      hp[j] = h; lp[j] = f32_bf16(c[j] - bf16_f32(h));
    }
    dhi[lane + 64 * i] = h4; dlo[lane + 64 * i] = l4;
  }
}

// ---------------- prep: m = 0.5*(state/|state| + adv/|adv|), split hi/lo ----------------
__global__ void __launch_bounds__(256) prep_m(const float* __restrict__ se,
                                              const float* __restrict__ ae,
                                              u16* __restrict__ m_hi,
                                              u16* __restrict__ m_lo) {
  const int lane = threadIdx.x & 63, wid = threadIdx.x >> 6;
  const size_t row = (size_t)blockIdx.x * 4 + wid;
  const float4* s = (const float4*)(se + row * D_DIM);
  const float4* a = (const float4*)(ae + row * D_DIM);
  float4 sv[2], av[2]; float ss = 0.f, sa = 0.f;
#pragma unroll
  for (int i = 0; i < 2; ++i) {
    sv[i] = s[lane + 64 * i]; av[i] = a[lane + 64 * i];
    ss = fmaf(sv[i].x, sv[i].x, ss); ss = fmaf(sv[i].y, sv[i].y, ss);
    ss = fmaf(sv[i].z, sv[i].z, ss); ss = fmaf(sv[i].w, sv[i].w, ss);
    sa = fmaf(av[i].x, av[i].x, sa); sa = fmaf(av[i].y, av[i].y, sa);
    sa = fmaf(av[i].z, av[i].z, sa); sa = fmaf(av[i].w, av[i].w, sa);
  }
#pragma unroll
  for (int off = 32; off; off >>= 1) { ss += __shfl_xor(ss, off); sa += __shfl_xor(sa, off); }
  const float is = 0.5f / fmaxf(sqrtf(ss), 1e-8f);
  const float ia = 0.5f / fmaxf(sqrtf(sa), 1e-8f);
  ushort4* dhi = (ushort4*)(m_hi + row * D_DIM);
  ushort4* dlo = (ushort4*)(m_lo + row * D_DIM);
#pragma unroll
  for (int i = 0; i < 2; ++i) {
    const float c[4] = {sv[i].x * is + av[i].x * ia, sv[i].y * is + av[i].y * ia,
                        sv[i].z * is + av[i].z * ia, sv[i].w * is + av[i].w * ia};
    ushort4 h4, l4;
    u16* hp = (u16*)&h4; u16* lp = (u16*)&l4;
#pragma unroll
    for (int j = 0; j < 4; ++j) {
      const u16 h = f32_bf16(c[j]);
      hp[j] = h; lp[j] = f32_bf16(c[j] - bf16_f32(h));
    }
    dhi[lane + 64 * i] = h4; dlo[lane + 64 * i] = l4;
  }
}

// ---------------- fused GEMM (bf16x2 split, 3-term) + gumbel epilogue ----------------
// 128x128 tile, BK=64, 256 threads (2x2 waves). Writes UNNORMALIZED exp(l2) to pw,
// accumulates per-row softmax sum (atomicAdd) and argmax (packed atomicMax) in ws.
__global__ void __launch_bounds__(256) fused_gemm_gumbel(const u16* __restrict__ mA_hi,
                                                         const u16* __restrict__ mA_lo,
                                                         const u16* __restrict__ cn_hi,
                                                         const u16* __restrict__ cn_lo,
                                                         float* __restrict__ pw,
                                                         float* __restrict__ ps_arr,
                                                         u64* __restrict__ bvpk,
                                                         u32 k1a, u32 k1b, u32 k2a, u32 k2b) {
  __shared__ __align__(16) u16 As_hi[128 * 64];
  __shared__ __align__(16) u16 As_lo[128 * 64];
  __shared__ __align__(16) u16 Bs_hi[128 * 64];
  __shared__ __align__(16) u16 Bs_lo[128 * 64];

  const int tid = threadIdx.x;
  const int lane = tid & 63;
  const int wid = tid >> 6;
  const int wr = wid >> 1, wc = wid & 1;
  const int bn = blockIdx.x, bm = blockIdx.y;

  const int fr = lane & 15; // A row / B col / C col
  const int q8 = lane >> 4; // k-group / C row-group

  f32x4 acc[4][4];
#pragma unroll
  for (int i = 0; i < 4; ++i)
#pragma unroll
    for (int j = 0; j < 4; ++j) acc[i][j] = (f32x4){0.f, 0.f, 0.f, 0.f};

  const int o_base = wid * 1024 + lane * 16;
  const char* gA_hi = (const char*)mA_hi + (size_t)(bm * 128) * (D_DIM * 2);
  const char* gA_lo = (const char*)mA_lo + (size_t)(bm * 128) * (D_DIM * 2);
  const char* gB_hi = (const char*)cn_hi + (size_t)(bn * 128) * (D_DIM * 2);
  const char* gB_lo = (const char*)cn_lo + (size_t)(bn * 128) * (D_DIM * 2);

  for (int kt = 0; kt < D_DIM / 64; ++kt) {
    const int kbyte = kt * 128;
#pragma unroll
    for (int i = 0; i < 4; ++i) {
      const int o = o_base + i * 4096;
      const int row = o >> 7;
      const int cbyt = o & 127;
      const size_t goff = (size_t)row * (D_DIM * 2) + kbyte + cbyt;
      const int loff = wid * 1024 + i * 4096;
      __builtin_amdgcn_global_load_lds((const __attribute__((address_space(1))) void*)(gA_hi + goff),
                                       (__attribute__((address_space(3))) void*)((char*)As_hi + loff), 16, 0, 0);
      __builtin_amdgcn_global_load_lds((const __attribute__((address_space(1))) void*)(gA_lo + goff),
                                       (__attribute__((address_space(3))) void*)((char*)As_lo + loff), 16, 0, 0);
      __builtin_amdgcn_global_load_lds((const __attribute__((address_space(1))) void*)(gB_hi + goff),
                                       (__attribute__((address_space(3))) void*)((char*)Bs_hi + loff), 16, 0, 0);
      __builtin_amdgcn_global_load_lds((const __attribute__((address_space(1))) void*)(gB_lo + goff),
                                       (__attribute__((address_space(3))) void*)((char*)Bs_lo + loff), 16, 0, 0);
    }
    __syncthreads();

#pragma unroll
    for (int kk = 0; kk < 2; ++kk) {
      bf16x8 ah[4], al[4], bh[4], bl[4];
      const int co = kk * 32 + q8 * 8;
#pragma unroll
      for (int mi = 0; mi < 4; ++mi) {
        const int r = wr * 64 + mi * 16 + fr;
        ah[mi] = *(const bf16x8*)&As_hi[r * 64 + co];
        al[mi] = *(const bf16x8*)&As_lo[r * 64 + co];
      }
#pragma unroll
      for (int ni = 0; ni < 4; ++ni) {
        const int r = wc * 64 + ni * 16 + fr;
        bh[ni] = *(const bf16x8*)&Bs_hi[r * 64 + co];
        bl[ni] = *(const bf16x8*)&Bs_lo[r * 64 + co];
      }
#pragma unroll
      for (int mi = 0; mi < 4; ++mi)
#pragma unroll
        for (int ni = 0; ni < 4; ++ni) {
          acc[mi][ni] = __builtin_amdgcn_mfma_f32_16x16x32_bf16(ah[mi], bh[ni], acc[mi][ni], 0, 0, 0);
          acc[mi][ni] = __builtin_amdgcn_mfma_f32_16x16x32_bf16(ah[mi], bl[ni], acc[mi][ni], 0, 0, 0);
          acc[mi][ni] = __builtin_amdgcn_mfma_f32_16x16x32_bf16(al[mi], bh[ni], acc[mi][ni], 0, 0, 0);
        }
    }
    __syncthreads();
  }

  // ---- fused gumbel epilogue on acc ----
  // C layout: col = lane&15 (fr), row = q8*4 + reg. exp un-shifted is safe:
  // l2 in [-5.5, 17.7] -> exp in [4e-3, 5e7]; row sum < 5e10 << f32 max.
  const u32 nrow0 = (u32)bm * 128u;
  const u32 col0 = (u32)(bn * 128 + wc * 64 + fr);
#pragma unroll
  for (int mi = 0; mi < 4; ++mi) {
#pragma unroll
    for (int r = 0; r < 4; ++r) {
      const u32 n = nrow0 + (u32)(wr * 64 + mi * 16 + q8 * 4 + r);
      const u32 kb = n * (u32)K_CB;
      float psum = 0.f; float lbv = -1e30f; u32 lbi = 0u;
#pragma unroll
      for (int ni = 0; ni < 4; ++ni) {
        const u32 k = col0 + (u32)(ni * 16);
        const float s = acc[mi][ni][r];
        u32 a0, a1, b0, b1;
        tf2x32(k1a, k1b, 0u, kb + k, a0, a1);
        tf2x32(k2a, k2b, 0u, kb + k, b0, b1);
        const float l1 = s + gumbel_fast(a0 ^ a1);
        const float p = __expf(s + gumbel_fast(b0 ^ b1));
        pw[(size_t)kb + k] = p;
        psum += p;
        if (l1 > lbv) { lbv = l1; lbi = k; } // ni ascending -> first-max kept
      }
#pragma unroll
      for (int off = 1; off < 16; off <<= 1) { // reduce across fr (cols)
        const float ov = __shfl_xor(lbv, off);
        const u32 oi = (u32)__shfl_xor((int)lbi, off);
        psum += __shfl_xor(psum, off);
        if (ov > lbv || (ov == lbv && oi < lbi)) { lbv = ov; lbi = oi; }
      }
      if (fr == 0) {
        atomicAdd(&ps_arr[n], psum);
        const u32 sb = __float_as_uint(lbv);
        const u32 key = (sb & 0x80000000u) ? ~sb : (sb | 0x80000000u); // sortable float
        const u64 pk = ((u64)key << 32) | (u64)(~lbi); // ~idx: smaller idx wins ties
        atomicMax(&bvpk[n], pk);
      }
    }
  }
}

// ---------------- final: normalize weights in place + z_q gather + indices ----------------
__global__ void __launch_bounds__(256) norm_gather(float* __restrict__ w,
                                                   float* __restrict__ zq,
                                                   float* __restrict__ idxf,
                                                   const float* __restrict__ ps_arr,
                                                   const u64* __restrict__ bvpk,
                                                   const float* __restrict__ cb) {
  const int lane = threadIdx.x & 63, wid = threadIdx.x >> 6;
  const int n = blockIdx.x * 4 + wid;
  const float inv = 1.0f / ps_arr[n];
  const u32 bi = ~((u32)bvpk[n]);
  float4* row4 = (float4*)(w + (size_t)n * K_CB);
#pragma unroll
  for (int i = 0; i < 4; ++i) {
    float4 v = row4[lane + i * 64];
    v.x *= inv; v.y *= inv; v.z *= inv; v.w *= inv;
    row4[lane + i * 64] = v;
  }
  const float4* crow = (const float4*)(cb + (size_t)bi * D_DIM);
  float4* zrow = (float4*)(zq + (size_t)n * D_DIM);
#pragma unroll
  for (int i = 0; i < 2; ++i) zrow[lane + i * 64] = crow[lane + i * 64];
  if (lane == 0) idxf[n] = (float)bi;
}

// ---------------- host ----------------
extern "C" void kernel_launch(void* const* d_in, const int* in_sizes, int n_in,
                              void* d_out, int out_size, void* d_ws, size_t ws_size,
                              hipStream_t stream) {
  const float* state = (const float*)d_in[0];
  const float* adv = (const float*)d_in[1];
  const float* cb = (const float*)d_in[2];

  char* ws = (char*)d_ws;
  size_t off = 0;
  u16* m_hi = (u16*)(ws + off); off += (size_t)N_ROWS * D_DIM * 2; // 32 MB
  u16* m_lo = (u16*)(ws + off); off += (size_t)N_ROWS * D_DIM * 2; // 32 MB
  u16* cn_hi = (u16*)(ws + off); off += (size_t)K_CB * D_DIM * 2;  // 1 MB
  u16* cn_lo = (u16*)(ws + off); off += (size_t)K_CB * D_DIM * 2;  // 1 MB
  float* ps_arr = (float*)(ws + off); off += (size_t)N_ROWS * 4;   // 128 KB
  u64* bvpk = (u64*)(ws + off); off += (size_t)N_ROWS * 8;         // 256 KB

  float* zq = (float*)d_out;                  // [N, D]
  float* w = zq + (size_t)N_ROWS * D_DIM;     // [N, K] unnormalized exp -> weights_soft
  float* idxf = w + (size_t)N_ROWS * K_CB;    // [N, 1] as float

  // jax.random.key(42) -> (0,42); partitionable fold-like split: gk1=E(0,0), gk2=E(0,1)
  u32 gk1a, gk1b, gk2a, gk2b;
  tf2x32(0u, 42u, 0u, 0u, gk1a, gk1b);
  tf2x32(0u, 42u, 0u, 1u, gk2a, gk2b);

  hipMemsetAsync(ps_arr, 0, (size_t)N_ROWS * 4, stream);
  hipMemsetAsync(bvpk, 0, (size_t)N_ROWS * 8, stream);
  hipLaunchKernelGGL(prep_codebook, dim3(K_CB / 4), dim3(256), 0, stream, cb, cn_hi, cn_lo);
  hipLaunchKernelGGL(prep_m, dim3(N_ROWS / 4), dim3(256), 0, stream, state, adv, m_hi, m_lo);
  hipLaunchKernelGGL(fused_gemm_gumbel, dim3(K_CB / 128, N_ROWS / 128), dim3(256), 0, stream,
                     m_hi, m_lo, cn_hi, cn_lo, w, ps_arr, bvpk, gk1a, gk1b, gk2a, gk2b);
  hipLaunchKernelGGL(norm_gather, dim3(N_ROWS / 4), dim3(256), 0, stream,
                     w, zq, idxf, ps_arr, bvpk, cb);
}